// Round 8
// baseline (262.181 us; speedup 1.0000x reference)
//
#include <hip/hip_runtime.h>
#include <math.h>

// Problem constants
#define B_   8
#define C_   64
#define H_   128
#define W_   128
#define HW_  16384
#define K2_  9

typedef float f32x4 __attribute__((ext_vector_type(4)));
typedef short bf16x8 __attribute__((ext_vector_type(8)));
typedef unsigned short u16x4 __attribute__((ext_vector_type(4)));

// Workspace layout (float offsets):
//   wrP  deform A-frags bf16    @ 8192     (36864 us)
//   wrP2 offmod A-frags bf16    @ 26624    (18432 us)
//   xt   [B][H][W][64] bf16     @ 45056    (2097152 us)
#define WS_WRP  8192
#define WS_WRP2 26624
#define WS_XT   45056

static __device__ __forceinline__ unsigned short f2bf(float x) {
    unsigned int u = __float_as_uint(x);
    unsigned int r = (u + 0x7fffu + ((u >> 16) & 1u)) >> 16;   // RNE
    return (unsigned short)r;
}
static __device__ __forceinline__ float bf2f(unsigned short u) {
    return __uint_as_float(((unsigned int)u) << 16);
}

// ---------------------------------------------------------------------------
// Kernel 1: 1x1 fuse conv as bf16 MFMA GEMM (LDS A-frag build, direct B loads)
// + weight packing for k_main folded into blocks 0..17.
// M=64 (o), N=64 (half row), K=128. grid = B*H*2 = 2048,
// blockIdx = (y*2+h)*8 + b. Wave wv owns px [h*64+wv*16, +16).
// A-frag convention (16x16x32): m = mt*16+(lane&15), k = kc*32+(lane>>4)*8+j.
// ---------------------------------------------------------------------------
__global__ __launch_bounds__(256) void k_fuse(const float* __restrict__ xi,
                                              const float* __restrict__ xc,
                                              const float* __restrict__ wf,
                                              const float* __restrict__ wreg,
                                              const float* __restrict__ wOff,
                                              const float* __restrict__ wMod,
                                              unsigned short* __restrict__ xtb,
                                              unsigned short* __restrict__ wrP,
                                              unsigned short* __restrict__ wrP2) {
    __shared__ unsigned short sA[1024 * 8];   // 16 KB: [f=kc*4+mt][lane][8]
    const int t = threadIdx.x;
    const int lane = t & 63;
    const int wv = t >> 6;
    const int b = blockIdx.x & 7;
    const int yh = blockIdx.x >> 3;
    const int y = yh >> 1;
    const int h = yh & 1;

    // ---- pack wrP / wrP2 (blocks 0..17 only; consumed by k_main) ----
    if (blockIdx.x < 18) {
        const int idx = blockIdx.x * 256 + t;
        if (idx < 4608) {
            int ln = idx & 63, mt = (idx >> 6) & 3, kc = (idx >> 8) & 1, tap = idx >> 9;
            int o = mt * 16 + (ln & 15);
            int ibase = kc * 32 + (ln >> 4) * 8;
#pragma unroll
            for (int j = 0; j < 8; ++j)
                wrP[idx * 8 + j] = f2bf(wreg[(o * 64 + ibase + j) * 9 + tap]);
        }
        if (idx < 2304) {
            int ln = idx & 63, mt = (idx >> 6) & 1, kc = idx >> 7;
            int m = mt * 16 + (ln & 15);
            int gkb = kc * 32 + (ln >> 4) * 8;
#pragma unroll
            for (int j = 0; j < 8; ++j) {
                int gk = gkb + j, tap = gk >> 6, ci = gk & 63;
                float v = 0.f;
                if (m < 18)      v = wOff[(m * 64 + ci) * 9 + tap];
                else if (m < 27) v = wMod[((m - 18) * 64 + ci) * 9 + tap];
                wrP2[idx * 8 + j] = f2bf(v);
            }
        }
    }

    // ---- build fuse A-frags in LDS ----
#pragma unroll
    for (int r = 0; r < 4; ++r) {
        const int c = t + 256 * r;      // chunk 0..1023
        const int f = c >> 6;           // f = kc*4 + mt
        const int ln = c & 63;
        const int mt = f & 3, kc = f >> 2;
        const int m = mt * 16 + (ln & 15);
        const int kb = kc * 32 + (ln >> 4) * 8;
        const float* s = wf + m * 128 + kb;
        unsigned short us[8];
#pragma unroll
        for (int j = 0; j < 8; ++j) us[j] = f2bf(s[j]);
        *(bf16x8*)&sA[c * 8] = *(const bf16x8*)us;
    }
    __syncthreads();

    const int n15 = lane & 15;
    const int q4 = lane >> 4;
    const int px = h * 64 + wv * 16 + n15;
    const size_t poff = (size_t)y * W_ + px;

    f32x4 acc[4];
#pragma unroll
    for (int mt = 0; mt < 4; ++mt) acc[mt] = (f32x4){0.f, 0.f, 0.f, 0.f};

#pragma unroll
    for (int kc = 0; kc < 4; ++kc) {
        const float* src = (kc < 2)
            ? (xi + ((size_t)(b * 64 + kc * 32 + q4 * 8)) * HW_ + poff)
            : (xc + ((size_t)(b * 64 + (kc - 2) * 32 + q4 * 8)) * HW_ + poff);
        unsigned short us[8];
#pragma unroll
        for (int j = 0; j < 8; ++j) us[j] = f2bf(src[(size_t)j * HW_]);
        const bf16x8 bf = *(const bf16x8*)us;
#pragma unroll
        for (int mt = 0; mt < 4; ++mt) {
            const bf16x8 a = *(const bf16x8*)&sA[((kc * 4 + mt) * 64 + lane) * 8];
            acc[mt] = __builtin_amdgcn_mfma_f32_16x16x32_bf16(a, bf, acc[mt], 0, 0, 0);
        }
    }

#pragma unroll
    for (int mt = 0; mt < 4; ++mt) {
        u16x4 o4;
        o4.x = f2bf(acc[mt][0]); o4.y = f2bf(acc[mt][1]);
        o4.z = f2bf(acc[mt][2]); o4.w = f2bf(acc[mt][3]);
        *(u16x4*)&xtb[((size_t)b * HW_ + poff) * 64 + mt * 16 + q4 * 4] = o4;
    }
}

// ---------------------------------------------------------------------------
// Kernel 2 (merged): 3x3 off+mod MFMA conv -> LDS om -> deformable sampling
// + modulation + bf16 MFMA einsum. grid = B*H*2 = 2048, 4 waves x 16 px.
// Phases:
//   1. Stage halo sB [3 rows][66 px][72-stride ch] bf16 (28.5 KB). barrier.
//   2. offmod MFMA (M=32/27, K=576), wave wv's D covers px [wv*16,+16). barrier.
//   3. Epilogue -> sOM[c 0..26][pxl 0..63] in LDS (aliased onto retired sB);
//      wave-private px, no further barriers.
//   4. Tap loop (9): Phase A per-lane (px x corner) record in regs;
//      Phase B lane=channel, readlane-broadcast saddr gathers from xtb;
//      einsum MFMA (72 total). All wave-private.
// ---------------------------------------------------------------------------
__global__ __launch_bounds__(256) void k_main(const unsigned short* __restrict__ xtb,
                                              const unsigned short* __restrict__ wrP,
                                              const unsigned short* __restrict__ wrP2,
                                              const float* __restrict__ bOff,
                                              const float* __restrict__ bMod,
                                              float* __restrict__ out) {
    __shared__ char smem[3 * 66 * 72 * 2];                    // 28512 B
    unsigned short* sB  = (unsigned short*)smem;              // phase 1-2
    float*          sOM = (float*)smem;                       // phase 3+: 6912 B
    unsigned short* sS2 = (unsigned short*)(smem + 8192);     // phase 4: 8320 B

    const int t = threadIdx.x;
    const int lane = t & 63;
    const int wv = t >> 6;
    const int b = blockIdx.x & 7;
    const int yh = blockIdx.x >> 3;
    const int y = yh >> 1;
    const int h = yh & 1;

    const int n15 = lane & 15;
    const int q4 = lane >> 4;

    // ---- Phase 1: stage halo tile ----
    for (int idx = t; idx < 3 * 66 * 8; idx += 256) {
        const int c8 = idx & 7;
        const int pp = (idx >> 3) % 66;
        const int row = (idx >> 3) / 66;
        const int gx = h * 64 + pp - 1;
        const int gy = y + row - 1;
        bf16x8 v = {0, 0, 0, 0, 0, 0, 0, 0};
        if (gx >= 0 && gx < W_ && gy >= 0 && gy < H_)
            v = *(const bf16x8*)&xtb[(((size_t)(b * H_ + gy)) * W_ + gx) * 64 + c8 * 8];
        *(bf16x8*)&sB[(row * 66 + pp) * 72 + c8 * 8] = v;
    }
    __syncthreads();

    // ---- Phase 2: offmod im2col MFMA ----
    f32x4 oacc[2];
    oacc[0] = (f32x4){0.f, 0.f, 0.f, 0.f};
    oacc[1] = (f32x4){0.f, 0.f, 0.f, 0.f};
#pragma unroll
    for (int kc = 0; kc < 18; ++kc) {
        const int gkb = kc * 32 + q4 * 8;
        const int tap = gkb >> 6;
        const int ci = gkb & 63;
        const int row = tap / 3, kx = tap % 3;
        const bf16x8 bf = *(const bf16x8*)&sB[(row * 66 + (wv * 16 + n15 + kx)) * 72 + ci];
        const bf16x8 a0 = *(const bf16x8*)(wrP2 + (((size_t)(kc * 2 + 0) * 64 + lane) * 8));
        const bf16x8 a1 = *(const bf16x8*)(wrP2 + (((size_t)(kc * 2 + 1) * 64 + lane) * 8));
        oacc[0] = __builtin_amdgcn_mfma_f32_16x16x32_bf16(a0, bf, oacc[0], 0, 0, 0);
        oacc[1] = __builtin_amdgcn_mfma_f32_16x16x32_bf16(a1, bf, oacc[1], 0, 0, 0);
    }
    __syncthreads();   // retire sB before aliasing as sOM

    // ---- Phase 3: off/mod epilogue -> sOM[c][pxl] (wave-private px) ----
    {
        const int pxl = wv * 16 + n15;
#pragma unroll
        for (int mt = 0; mt < 2; ++mt)
#pragma unroll
            for (int r = 0; r < 4; ++r) {
                const int o = mt * 16 + q4 * 4 + r;
                if (o < 18) {
                    const int c = (o >> 1) + ((o & 1) ? 9 : 0);
                    sOM[c * 64 + pxl] = oacc[mt][r] + bOff[o];
                } else if (o < 27) {
                    const float z = oacc[mt][r] + bMod[o - 18];
                    sOM[(18 + (o - 18)) * 64 + pxl] = 2.f / (1.f + __expf(-z));
                }
            }
    }

    // ---- Phase 4: deform tap loop ----
    const char* xbB = (const char*)(xtb + (size_t)b * HW_ * 64);
    const int pA = lane >> 2;        // phase-A px-local (0..15) within wave
    const int corner = lane & 3;     // 0=(y0,x0) 1=(y0,x1) 2=(y1,x0) 3=(y1,x1)
    const int cy = corner >> 1, cx = corner & 1;
    const int pxAl = wv * 16 + pA;             // local px 0..63
    const int pxA = h * 64 + pxAl;             // global px
    const int gwrite = (lane >> 3) * 520 + (lane & 7);

    f32x4 acc[4];
#pragma unroll
    for (int mt = 0; mt < 4; ++mt) acc[mt] = (f32x4){0.f, 0.f, 0.f, 0.f};

    for (int k = 0; k < 9; ++k) {
        const int ky = k / 3 - 1, kx = k % 3 - 1;

        // ---- Phase A: one (offset, weight) per lane, in registers ----
        int rOff;
        int rW;
        {
            const float dy = sOM[k * 64 + pxAl];
            const float dxv = sOM[(9 + k) * 64 + pxAl];
            const float m = sOM[(18 + k) * 64 + pxAl];
            const float py  = (float)(y + ky) + dy;
            const float pxe = (float)(pxA + kx) + dxv;
            const float y0f = floorf(py), x0f = floorf(pxe);
            const int y0i = (int)y0f, x0i = (int)x0f;
            const float wy1 = py - y0f, wx1 = pxe - x0f;
            const int yy = y0i + cy;
            const int xx = x0i + cx;
            const bool ok = (yy >= 0) && (yy < H_) && (xx >= 0) && (xx < W_);
            const int yc = min(max(yy, 0), H_ - 1);
            const int xc = min(max(xx, 0), W_ - 1);
            const float w = (cy ? wy1 : 1.f - wy1) * (cx ? wx1 : 1.f - wx1) * m;
            rOff = (yc * W_ + xc) * 128;     // byte offset (64 ch x bf16)
            rW = (int)__float_as_uint(ok ? w : 0.f);
        }

        // ---- Phase B: lane = channel; records via readlane (SGPR broadcast) --
#pragma unroll
        for (int p = 0; p < 16; ++p) {
            const int l0 = p * 4;
            const unsigned o0 = (unsigned)__builtin_amdgcn_readlane(rOff, l0 + 0);
            const unsigned o1 = (unsigned)__builtin_amdgcn_readlane(rOff, l0 + 1);
            const unsigned o2 = (unsigned)__builtin_amdgcn_readlane(rOff, l0 + 2);
            const unsigned o3 = (unsigned)__builtin_amdgcn_readlane(rOff, l0 + 3);
            const float w0 = __uint_as_float((unsigned)__builtin_amdgcn_readlane(rW, l0 + 0));
            const float w1 = __uint_as_float((unsigned)__builtin_amdgcn_readlane(rW, l0 + 1));
            const float w2 = __uint_as_float((unsigned)__builtin_amdgcn_readlane(rW, l0 + 2));
            const float w3 = __uint_as_float((unsigned)__builtin_amdgcn_readlane(rW, l0 + 3));
            const unsigned short* b0 = (const unsigned short*)(xbB + o0);
            const unsigned short* b1 = (const unsigned short*)(xbB + o1);
            const unsigned short* b2 = (const unsigned short*)(xbB + o2);
            const unsigned short* b3 = (const unsigned short*)(xbB + o3);
            const float v = bf2f(b0[lane]) * w0 + bf2f(b1[lane]) * w1
                          + bf2f(b2[lane]) * w2 + bf2f(b3[lane]) * w3;
            sS2[gwrite + (wv * 16 + p) * 8] = f2bf(v);
        }

        // ---- MFMA (wave-private B reads) ----
#pragma unroll
        for (int kc = 0; kc < 2; ++kc) {
            const bf16x8 bf = *(const bf16x8*)&sS2[(kc * 4 + q4) * 520 + (wv * 16 + n15) * 8];
#pragma unroll
            for (int mt = 0; mt < 4; ++mt) {
                const bf16x8 a = *(const bf16x8*)(wrP +
                    ((((size_t)((k * 2 + kc) * 4 + mt)) * 64 + lane) * 8));
                acc[mt] = __builtin_amdgcn_mfma_f32_16x16x32_bf16(a, bf, acc[mt], 0, 0, 0);
            }
        }
    }

    // epilogue: D[o = mt*16 + q4*4 + r][px = h*64 + wv*16 + n15], out NCHW
    const int px = h * 64 + wv * 16 + n15;
#pragma unroll
    for (int mt = 0; mt < 4; ++mt)
#pragma unroll
        for (int r = 0; r < 4; ++r) {
            const int o = mt * 16 + q4 * 4 + r;
            out[(((size_t)(b * 64 + o)) * H_ + y) * W_ + px] = acc[mt][r];
        }
}

// ---------------------------------------------------------------------------
extern "C" void kernel_launch(void* const* d_in, const int* in_sizes, int n_in,
                              void* d_out, int out_size, void* d_ws, size_t ws_size,
                              hipStream_t stream) {
    const float* x_img  = (const float*)d_in[0];
    const float* x_cont = (const float*)d_in[1];
    const float* w_fuse = (const float*)d_in[2];
    const float* w_off  = (const float*)d_in[3];
    const float* b_off  = (const float*)d_in[4];
    const float* w_mod  = (const float*)d_in[5];
    const float* b_mod  = (const float*)d_in[6];
    const float* w_reg  = (const float*)d_in[7];
    float* out = (float*)d_out;

    float* ws  = (float*)d_ws;
    unsigned short* wrP  = (unsigned short*)(ws + WS_WRP);
    unsigned short* wrP2 = (unsigned short*)(ws + WS_WRP2);
    unsigned short* xtb  = (unsigned short*)(ws + WS_XT);

    k_fuse<<<B_ * H_ * 2, 256, 0, stream>>>(x_img, x_cont, w_fuse, w_reg, w_off,
                                            w_mod, xtb, wrP, wrP2);
    k_main<<<B_ * H_ * 2, 256, 0, stream>>>(xtb, wrP, wrP2, b_off, b_mod, out);
}